// Round 4
// baseline (55.000 us; speedup 1.0000x reference)
//
#include <hip/hip_runtime.h>

#define NUM_SLICE 32

// Problem constants (fixed by setup_inputs)
constexpr int Bc = 8;
constexpr int Cc = 128;
constexpr int Nc = 65536;

// Tiling (R0 config: measured faster than 2048-block variant)
constexpr int CPB     = 8;     // channels per block
constexpr int CHUNK   = 8192;  // points (n) per block
constexpr int THREADS = 256;
constexpr int PTS_PER_ITER = THREADS * 4;      // 1024 points / iter (float4)
constexpr int NITER   = CHUNK / PTS_PER_ITER;  // 8
constexpr int NREP    = 4;     // replicas by lane&3: cuts same-addr atomic passes
constexpr int REP_LD  = 40;    // stride per (c,rep) row: bank = (8*rep + s) % 32

typedef float f32x4 __attribute__((ext_vector_type(4)));
typedef int   i32x4 __attribute__((ext_vector_type(4)));

__global__ __launch_bounds__(THREADS) void init_out_kernel(float* out, int n) {
    int i = blockIdx.x * blockDim.x + threadIdx.x;
    if (i < n) out[i] = 0.0f;
}

__global__ __launch_bounds__(THREADS) void slice_pool_kernel(
    const float* __restrict__ in,       // [B, C, N]
    const int*   __restrict__ idx,      // [B, N], values in [0, 32)
    unsigned int* __restrict__ out)     // [B, C, 32] as uint bits (all >= 0)
{
    // acc[(c*NREP + rep)*REP_LD + s]; REP_LD=40 => addr%32 = (8*rep + s)%32:
    // replicas occupy bank windows shifted by 8, so replica lanes never bank-collide.
    __shared__ unsigned int acc[CPB * NREP * REP_LD];

    const int t = threadIdx.x;
    for (int i = t; i < CPB * NREP * REP_LD; i += THREADS) acc[i] = 0u;
    __syncthreads();

    const int chunk = blockIdx.x;           // 0..7
    const int cg    = blockIdx.y;           // 0..15
    const int b     = blockIdx.z;           // 0..7
    const int c0    = cg * CPB;
    const int n0    = chunk * CHUNK;
    const int rep   = t & (NREP - 1);       // lane-parity replica (0..3)

    const i32x4* __restrict__ idx4   = (const i32x4*)(idx + (size_t)b * Nc + n0);
    const float* __restrict__ inbase = in + ((size_t)b * Cc + c0) * Nc + n0;

    unsigned int* __restrict__ accr = acc + rep * REP_LD;

    #pragma unroll 2
    for (int p = 0; p < NITER; ++p) {
        const int e    = p * THREADS + t;  // int4 slot within chunk
        const i32x4 iv = idx4[e];
        const int off  = e * 4;            // element offset within chunk
        #pragma unroll
        for (int c = 0; c < CPB; ++c) {
            const f32x4 v = *(const f32x4*)(inbase + (size_t)c * Nc + off);
            const int base = c * (NREP * REP_LD);
            // fmax(x,0) == 0 bits iff x <= 0: those atomics are no-ops vs the
            // zero-initialized accumulator -> skip (halves active lanes).
            const unsigned int bx = __float_as_uint(fmaxf(v[0], 0.0f));
            const unsigned int by = __float_as_uint(fmaxf(v[1], 0.0f));
            const unsigned int bz = __float_as_uint(fmaxf(v[2], 0.0f));
            const unsigned int bw = __float_as_uint(fmaxf(v[3], 0.0f));
            if (bx) atomicMax(&accr[base + iv[0]], bx);
            if (by) atomicMax(&accr[base + iv[1]], by);
            if (bz) atomicMax(&accr[base + iv[2]], bz);
            if (bw) atomicMax(&accr[base + iv[3]], bw);
        }
    }
    __syncthreads();

    // Epilogue: one thread per (channel, slice); merge replicas -> global max
    if (t < CPB * NUM_SLICE) {
        const int c = t >> 5;
        const int s = t & 31;
        unsigned int v = 0u;
        #pragma unroll
        for (int r = 0; r < NREP; ++r) {
            const unsigned int vr = acc[(c * NREP + r) * REP_LD + s];
            v = v > vr ? v : vr;
        }
        if (v != 0u) {
            atomicMax(&out[(((size_t)b * Cc) + c0 + c) * NUM_SLICE + s], v);
        }
    }
}

extern "C" void kernel_launch(void* const* d_in, const int* in_sizes, int n_in,
                              void* d_out, int out_size, void* d_ws, size_t ws_size,
                              hipStream_t stream) {
    const float* in  = (const float*)d_in[0];   // [8,128,65536,1] f32
    const int*   idx = (const int*)  d_in[1];   // [8,65536] i32
    float* out = (float*)d_out;                 // [8,128,32,1] f32

    // Zero the output every launch (harness poisons d_out, never re-poisons).
    const int n_out = Bc * Cc * NUM_SLICE;      // 32768
    init_out_kernel<<<(n_out + THREADS - 1) / THREADS, THREADS, 0, stream>>>(out, n_out);

    dim3 grid(Nc / CHUNK, Cc / CPB, Bc);        // (8, 16, 8) = 1024 blocks
    slice_pool_kernel<<<grid, THREADS, 0, stream>>>(in, idx, (unsigned int*)out);
}